// Round 12
// baseline (2589.973 us; speedup 1.0000x reference)
//
#include <hip/hip_runtime.h>

#define NN 40000
#define EE 640000
#define DD 128
#define LL 5
#define NB 157          // buckets of 256 dst nodes
#define CAP 8192        // slots per bucket (mean ~4076, sigma ~64)
#define GRID 1250       // persistent blocks, one 32-row tile each

typedef unsigned short u16;
typedef unsigned int   u32;
typedef __attribute__((ext_vector_type(8))) short bf8;   // 8 bf16 = 4 VGPRs
typedef __attribute__((ext_vector_type(4))) float f4;

__device__ __forceinline__ float bf2f(u32 u){ union{u32 i; float f;} x; x.i = u << 16; return x.f; }
__device__ __forceinline__ u16 f2bf(float f){
  union{float f; u32 i;} x; x.f = f;
  u32 r = x.i + 0x7FFFu + ((x.i >> 16) & 1u);
  return (u16)(r >> 16);
}
__device__ __forceinline__ u32 pack2(float a, float b){ return (u32)f2bf(a) | ((u32)f2bf(b) << 16); }

// grid barrier: all GRID blocks co-resident (launch_bounds(256,5), 21.5KB LDS -> 5 blocks/CU).
// Timeout valve: breaks a (theoretically impossible) deadlock into a wrong answer, not a hang.
__device__ __forceinline__ void gsync(int* bar, int target){
  __syncthreads();
  if (threadIdx.x == 0){
    __hip_atomic_fetch_add(bar, 1, __ATOMIC_ACQ_REL, __HIP_MEMORY_SCOPE_AGENT);
    int spins = 0;
    while (__hip_atomic_load(bar, __ATOMIC_ACQUIRE, __HIP_MEMORY_SCOPE_AGENT) < target){
      __builtin_amdgcn_s_sleep(2);
      if (++spins > 20000000) break;
    }
  }
  __syncthreads();
}

// ---------------- prologue A: init h/hb/deg/gcur/sentinel | wprep ----------------
__global__ void k_pre(const int* __restrict__ x_ids, const float* __restrict__ atom_emb,
                      float* __restrict__ h, u32* __restrict__ hb, int* __restrict__ deg,
                      const float* __restrict__ W1, const float* __restrict__ W2,
                      u16* __restrict__ wt, int* __restrict__ gcur){
  int bid = blockIdx.x, tid = threadIdx.x;
  if (bid < 5000){                                // init: NN*32 items (4 feats/thread)
    int idx = bid * 256 + tid;
    if (idx < NN) deg[idx] = 0;
    if (idx < 160) gcur[idx] = 0;
    if (idx < 32){ uint2 s; s.x = 0xFF80FF80u; s.y = 0xFF80FF80u;  // dummy node row: -inf
      ((uint2*)(hb + NN * 64))[idx] = s; }
    int n = idx >> 5, d4 = idx & 31;
    float4 v = ((const float4*)(atom_emb + x_ids[n] * DD))[d4];
    ((float4*)h)[idx] = v;
    uint2 hp; hp.x = pack2(v.x, v.y); hp.y = pack2(v.z, v.w);
    ((uint2*)hb)[idx] = hp;
  } else {                                        // wprep: 10*16384 items
    int idx = (bid - 5000) * 256 + tid;
    int m = idx >> 14, nk = idx & 16383;
    int n = nk >> 7, k = nk & 127;
    const float* src = (m < LL) ? (W1 + m * 16384) : (W2 + (m - LL) * 16384);
    wt[idx] = f2bf(src[k * DD + n]);
  }
}

// ---------------- prologue B: count degrees + bucket edges ----------------
__global__ __launch_bounds__(1024) void k_bin(const int* __restrict__ ei, const int* __restrict__ ea,
                                              int* __restrict__ deg, int* __restrict__ gcur,
                                              u32* __restrict__ store){
  __shared__ int l_cnt[160];
  __shared__ int l_base[160];
  int tid = threadIdx.x;
  if (tid < 160) l_cnt[tid] = 0;
  __syncthreads();
  int e0 = blockIdx.x * 4096;                     // 157 x 4096 >= EE
  u32 rec[4]; int rb[4], rr[4];
  #pragma unroll
  for (int j = 0; j < 4; ++j){
    int e = e0 + j * 1024 + tid;
    rb[j] = -1;
    if (e < EE){
      int dst = ei[EE + e];
      atomicAdd(&deg[dst], 1);
      int b = dst >> 8;
      rb[j] = b;
      rr[j] = atomicAdd(&l_cnt[b], 1);
      rec[j] = (u32)ei[e] | ((u32)ea[e] << 16) | ((u32)(dst & 255) << 18);
    }
  }
  __syncthreads();
  if (tid < 160) l_base[tid] = atomicAdd(&gcur[tid], l_cnt[tid]);
  __syncthreads();
  #pragma unroll
  for (int j = 0; j < 4; ++j)
    if (rb[j] >= 0)
      store[rb[j] * CAP + l_base[rb[j]] + rr[j]] = rec[j];
}

// phase 1: per-block exclusive scan of degrees padded to x4
__global__ void k_scan1(const int* __restrict__ deg, int* __restrict__ rs, int* __restrict__ bsum){
  __shared__ int buf[1024];
  int tid = threadIdx.x;
  int i = blockIdx.x * 1024 + tid;
  int dv = (i < NN) ? deg[i] : 0;
  int v = (dv + 3) & ~3;
  buf[tid] = v;
  __syncthreads();
  for (int off = 1; off < 1024; off <<= 1){
    int t = (tid >= off) ? buf[tid - off] : 0;
    __syncthreads();
    buf[tid] += t;
    __syncthreads();
  }
  int incl = buf[tid];
  if (i < NN) rs[i] = incl - v;
  if (tid == 1023) bsum[blockIdx.x] = incl;
}

// ---------------- place2: scan2-inline + scatter + sentinel + stats1/bar zero ----------------
__global__ __launch_bounds__(1024) void k_place2(const u32* __restrict__ store, const int* __restrict__ gcur,
                                                 const int* __restrict__ rs, int* __restrict__ rs2,
                                                 int* __restrict__ col, const int* __restrict__ bsum,
                                                 float* __restrict__ stats1, int* __restrict__ bar){
  __shared__ int l_cur[256];
  __shared__ int s_choff[41];
  int b = blockIdx.x, tid = threadIdx.x;
  if (b == 0){
    stats1[tid] = 0.f; stats1[1024 + tid] = 0.f;
    if (tid == 0) *bar = 0;
  }
  if (tid < 64){
    int v = (tid < 40) ? bsum[tid] : 0;
    #pragma unroll
    for (int off = 1; off < 64; off <<= 1){
      int t = __shfl_up(v, off, 64);
      if (tid >= off) v += t;
    }
    if (tid < 40){
      s_choff[tid] = v - bsum[tid];
      if (tid == 39) s_choff[40] = v;
    }
  }
  __syncthreads();
  int n0 = b << 8;
  if (tid < 256){
    int n = n0 + tid;
    if (n < NN){
      int g = rs[n] + s_choff[n >> 10];
      l_cur[tid] = g;
      rs2[n] = g;
    }
  }
  if (b == NB - 1 && tid == 0) rs2[NN] = s_choff[40];
  __syncthreads();
  int cnt = gcur[b];
  for (int r = tid; r < cnt; r += 1024){
    u32 rec = store[b * CAP + r];
    int dl = rec >> 18;
    int pos = atomicAdd(&l_cur[dl], 1);
    col[pos] = (int)((rec & 0xFFFFu) | (((rec >> 16) & 3u) << 20));
  }
  __syncthreads();
  if (tid < 256){
    int n = n0 + tid;
    if (n < NN){
      int e = l_cur[tid];
      int end = (n + 1 < NN) ? (rs[n + 1] + s_choff[(n + 1) >> 10]) : s_choff[40];
      for (; e < end; ++e) col[e] = NN;
    }
  }
}

// ---------------- persistent fused loop: 5 layers, 3 phases/layer, grid barrier between ----------------
// block b owns rows 32b..32b+31 across all phases/layers; z2b/zAb live in LDS only.
__global__ __launch_bounds__(256, 5) void k_loop(
    float* __restrict__ h, u32* __restrict__ hb,
    const int* __restrict__ rs2, const int* __restrict__ col,
    const float* __restrict__ bond_emb, const float* __restrict__ eps,
    const u16* __restrict__ wt, const float* __restrict__ b1,
    const float* __restrict__ g1, const float* __restrict__ bt1,
    const float* __restrict__ b2, const float* __restrict__ g_out,
    const float* __restrict__ b_out, float* __restrict__ stats, int* __restrict__ bar){
  __shared__ u16 bufA[32 * 136];     // phase1: z tile; phase2 out: y2 tile; phase3 reads
  __shared__ u16 bufB[32 * 136];     // phase1 out: y1 tile; phase2 reads
  __shared__ float2 s_bond[256];
  __shared__ float s_eps;
  __shared__ float s_scale[DD], s_shift[DD], s_sum[DD], s_sq[DD];
  int tid = threadIdx.x;
  int w = tid >> 6, lane = tid & 63;
  int lr = lane & 15, lk = lane >> 4;
  int row0 = blockIdx.x * 32;
  int ep = 0;
  float* stats1 = stats;
  float* stats2 = stats + 2048;
  #pragma unroll 1
  for (int l = 0; l < LL; ++l){
    // ================= phase 1: gather + GEMM1 =================
    if (blockIdx.x == 0){                         // zero stats2 for this layer
      #pragma unroll
      for (int j = 0; j < 8; ++j) stats2[j * 256 + tid] = 0.f;
    }
    if (tid < 256) s_bond[tid] = ((const float2*)(bond_emb + l * 4 * DD))[tid];
    if (tid == 0) s_eps = 1.0f + eps[l];
    if (tid < DD){ s_sum[tid] = 0.f; s_sq[tid] = 0.f; }
    __syncthreads();
    {
      int vbase = row0 + w * 8;
      int sprev = __builtin_amdgcn_readfirstlane(rs2[vbase]);
      for (int j = 0; j < 8; ++j){
        int v = vbase + j;
        int send = __builtin_amdgcn_readfirstlane(rs2[v + 1]);   // multiple of 4
        int i = sprev; sprev = send;
        float a0 = 0.f, a1 = 0.f, b0 = 0.f, b1v = 0.f, c0 = 0.f, c1 = 0.f, d0 = 0.f, d1 = 0.f;
        for (; i + 8 <= send; i += 8){
          int4 ca = *(const int4*)(col + i);
          int4 cb = *(const int4*)(col + i + 4);
          u32 h0 = hb[(ca.x & 0xFFFFF) * 64 + lane];
          u32 h1 = hb[(ca.y & 0xFFFFF) * 64 + lane];
          u32 h2 = hb[(ca.z & 0xFFFFF) * 64 + lane];
          u32 h3 = hb[(ca.w & 0xFFFFF) * 64 + lane];
          u32 h4 = hb[(cb.x & 0xFFFFF) * 64 + lane];
          u32 h5 = hb[(cb.y & 0xFFFFF) * 64 + lane];
          u32 h6 = hb[(cb.z & 0xFFFFF) * 64 + lane];
          u32 h7 = hb[(cb.w & 0xFFFFF) * 64 + lane];
          float2 bb0 = s_bond[(ca.x >> 20) * 64 + lane];
          float2 bb1 = s_bond[(ca.y >> 20) * 64 + lane];
          float2 bb2 = s_bond[(ca.z >> 20) * 64 + lane];
          float2 bb3 = s_bond[(ca.w >> 20) * 64 + lane];
          float2 bb4 = s_bond[(cb.x >> 20) * 64 + lane];
          float2 bb5 = s_bond[(cb.y >> 20) * 64 + lane];
          float2 bb6 = s_bond[(cb.z >> 20) * 64 + lane];
          float2 bb7 = s_bond[(cb.w >> 20) * 64 + lane];
          a0 += fmaxf(bf2f(h0 & 0xFFFFu) + bb0.x, 0.f);
          a1 += fmaxf(bf2f(h0 >> 16)     + bb0.y, 0.f);
          b0 += fmaxf(bf2f(h1 & 0xFFFFu) + bb1.x, 0.f);
          b1v+= fmaxf(bf2f(h1 >> 16)     + bb1.y, 0.f);
          c0 += fmaxf(bf2f(h2 & 0xFFFFu) + bb2.x, 0.f);
          c1 += fmaxf(bf2f(h2 >> 16)     + bb2.y, 0.f);
          d0 += fmaxf(bf2f(h3 & 0xFFFFu) + bb3.x, 0.f);
          d1 += fmaxf(bf2f(h3 >> 16)     + bb3.y, 0.f);
          a0 += fmaxf(bf2f(h4 & 0xFFFFu) + bb4.x, 0.f);
          a1 += fmaxf(bf2f(h4 >> 16)     + bb4.y, 0.f);
          b0 += fmaxf(bf2f(h5 & 0xFFFFu) + bb5.x, 0.f);
          b1v+= fmaxf(bf2f(h5 >> 16)     + bb5.y, 0.f);
          c0 += fmaxf(bf2f(h6 & 0xFFFFu) + bb6.x, 0.f);
          c1 += fmaxf(bf2f(h6 >> 16)     + bb6.y, 0.f);
          d0 += fmaxf(bf2f(h7 & 0xFFFFu) + bb7.x, 0.f);
          d1 += fmaxf(bf2f(h7 >> 16)     + bb7.y, 0.f);
        }
        if (i < send){                            // exactly 4 remain
          int4 ca = *(const int4*)(col + i);
          u32 h0 = hb[(ca.x & 0xFFFFF) * 64 + lane];
          u32 h1 = hb[(ca.y & 0xFFFFF) * 64 + lane];
          u32 h2 = hb[(ca.z & 0xFFFFF) * 64 + lane];
          u32 h3 = hb[(ca.w & 0xFFFFF) * 64 + lane];
          float2 bb0 = s_bond[(ca.x >> 20) * 64 + lane];
          float2 bb1 = s_bond[(ca.y >> 20) * 64 + lane];
          float2 bb2 = s_bond[(ca.z >> 20) * 64 + lane];
          float2 bb3 = s_bond[(ca.w >> 20) * 64 + lane];
          a0 += fmaxf(bf2f(h0 & 0xFFFFu) + bb0.x, 0.f);
          a1 += fmaxf(bf2f(h0 >> 16)     + bb0.y, 0.f);
          b0 += fmaxf(bf2f(h1 & 0xFFFFu) + bb1.x, 0.f);
          b1v+= fmaxf(bf2f(h1 >> 16)     + bb1.y, 0.f);
          c0 += fmaxf(bf2f(h2 & 0xFFFFu) + bb2.x, 0.f);
          c1 += fmaxf(bf2f(h2 >> 16)     + bb2.y, 0.f);
          d0 += fmaxf(bf2f(h3 & 0xFFFFu) + bb3.x, 0.f);
          d1 += fmaxf(bf2f(h3 >> 16)     + bb3.y, 0.f);
        }
        float2 hv = ((const float2*)h)[v * 64 + lane];
        u32 zp = pack2(s_eps * hv.x + a0 + b0 + c0 + d0,
                       s_eps * hv.y + a1 + b1v + c1 + d1);
        *(u32*)(bufA + (w * 8 + j) * 136 + lane * 2) = zp;
      }
    }
    // B fragments for GEMM1
    const u16* Wt1 = wt + l * 16384;
    bf8 bfr[2][4];
    #pragma unroll
    for (int nt = 0; nt < 2; ++nt){
      int n = w * 32 + nt * 16 + lr;
      #pragma unroll
      for (int kt = 0; kt < 4; ++kt)
        bfr[nt][kt] = *(const bf8*)(Wt1 + n * DD + kt * 32 + lk * 8);
    }
    __syncthreads();
    {
      f4 acc[2][2];
      #pragma unroll
      for (int mt = 0; mt < 2; ++mt)
        #pragma unroll
        for (int nt = 0; nt < 2; ++nt) acc[mt][nt] = (f4){0.f, 0.f, 0.f, 0.f};
      #pragma unroll
      for (int kt = 0; kt < 4; ++kt){
        bf8 a0 = *(const bf8*)(bufA + lr * 136        + kt * 32 + lk * 8);
        bf8 a1 = *(const bf8*)(bufA + (16 + lr) * 136 + kt * 32 + lk * 8);
        acc[0][0] = __builtin_amdgcn_mfma_f32_16x16x32_bf16(a0, bfr[0][kt], acc[0][0], 0, 0, 0);
        acc[0][1] = __builtin_amdgcn_mfma_f32_16x16x32_bf16(a0, bfr[1][kt], acc[0][1], 0, 0, 0);
        acc[1][0] = __builtin_amdgcn_mfma_f32_16x16x32_bf16(a1, bfr[0][kt], acc[1][0], 0, 0, 0);
        acc[1][1] = __builtin_amdgcn_mfma_f32_16x16x32_bf16(a1, bfr[1][kt], acc[1][1], 0, 0, 0);
      }
      const float* b1l = b1 + l * DD;
      #pragma unroll
      for (int nt = 0; nt < 2; ++nt){
        int colg = w * 32 + nt * 16 + lr;
        float bv = b1l[colg];
        float cs = 0.f, cq = 0.f;
        #pragma unroll
        for (int mt = 0; mt < 2; ++mt){
          #pragma unroll
          for (int r = 0; r < 4; ++r){
            u16 yb = f2bf(acc[mt][nt][r] + bv);
            float yr = bf2f(yb);
            bufB[(mt * 16 + lk * 4 + r) * 136 + colg] = yb;
            cs += yr; cq += yr * yr;
          }
        }
        atomicAdd(&s_sum[colg], cs);
        atomicAdd(&s_sq[colg], cq);
      }
    }
    __syncthreads();
    {
      float* slice = stats1 + (blockIdx.x & 7) * 256;
      if (tid < DD){
        atomicAdd(&slice[tid],      s_sum[tid]);
        atomicAdd(&slice[DD + tid], s_sq[tid]);
      }
    }
    gsync(bar, (++ep) * GRID);
    // ================= phase 2: BN1+ReLU + GEMM2 (bufB -> bufA) =================
    if (tid < DD){
      float s = 0.f, q = 0.f;
      #pragma unroll
      for (int s8 = 0; s8 < 8; ++s8){
        s += stats1[s8 * 256 + tid];
        q += stats1[s8 * 256 + DD + tid];
      }
      float m   = s * (1.0f / NN);
      float var = q * (1.0f / NN) - m * m;
      float inv = rsqrtf(var + 1e-5f);
      float sc  = inv * g1[l * DD + tid];
      s_scale[tid] = sc;
      s_shift[tid] = bt1[l * DD + tid] - m * sc;
      s_sum[tid] = 0.f; s_sq[tid] = 0.f;
    }
    __syncthreads();
    {
      const u16* Wt2 = wt + (LL + l) * 16384;
      f4 acc[2][2];
      #pragma unroll
      for (int mt = 0; mt < 2; ++mt)
        #pragma unroll
        for (int nt = 0; nt < 2; ++nt) acc[mt][nt] = (f4){0.f, 0.f, 0.f, 0.f};
      #pragma unroll
      for (int kt = 0; kt < 4; ++kt){
        int c = kt * 32 + lk * 8;
        float4 sc0 = *(const float4*)(s_scale + c);
        float4 sc1 = *(const float4*)(s_scale + c + 4);
        float4 sh0 = *(const float4*)(s_shift + c);
        float4 sh1 = *(const float4*)(s_shift + c + 4);
        float scv[8] = {sc0.x, sc0.y, sc0.z, sc0.w, sc1.x, sc1.y, sc1.z, sc1.w};
        float shv[8] = {sh0.x, sh0.y, sh0.z, sh0.w, sh1.x, sh1.y, sh1.z, sh1.w};
        bf8 afr[2];
        #pragma unroll
        for (int mt = 0; mt < 2; ++mt){
          uint4 zv = *(const uint4*)(bufB + (mt * 16 + lr) * 136 + c);
          u32 zw[4] = {zv.x, zv.y, zv.z, zv.w};
          union { u16 o[8]; bf8 v; } u;
          #pragma unroll
          for (int j = 0; j < 4; ++j){
            float y0 = fmaxf(bf2f(zw[j] & 0xFFFFu) * scv[2*j]     + shv[2*j],     0.f);
            float y1 = fmaxf(bf2f(zw[j] >> 16)     * scv[2*j + 1] + shv[2*j + 1], 0.f);
            u.o[2*j]     = f2bf(y0);
            u.o[2*j + 1] = f2bf(y1);
          }
          afr[mt] = u.v;
        }
        bf8 bf0 = *(const bf8*)(Wt2 + (w * 32 + lr) * DD + c);
        bf8 bf1 = *(const bf8*)(Wt2 + (w * 32 + 16 + lr) * DD + c);
        acc[0][0] = __builtin_amdgcn_mfma_f32_16x16x32_bf16(afr[0], bf0, acc[0][0], 0, 0, 0);
        acc[0][1] = __builtin_amdgcn_mfma_f32_16x16x32_bf16(afr[0], bf1, acc[0][1], 0, 0, 0);
        acc[1][0] = __builtin_amdgcn_mfma_f32_16x16x32_bf16(afr[1], bf0, acc[1][0], 0, 0, 0);
        acc[1][1] = __builtin_amdgcn_mfma_f32_16x16x32_bf16(afr[1], bf1, acc[1][1], 0, 0, 0);
      }
      const float* b2l = b2 + l * DD;
      #pragma unroll
      for (int nt = 0; nt < 2; ++nt){
        int colg = w * 32 + nt * 16 + lr;
        float bv = b2l[colg];
        float cs = 0.f, cq = 0.f;
        #pragma unroll
        for (int mt = 0; mt < 2; ++mt){
          #pragma unroll
          for (int r = 0; r < 4; ++r){
            u16 yb = f2bf(acc[mt][nt][r] + bv);
            float yr = bf2f(yb);
            bufA[(mt * 16 + lk * 4 + r) * 136 + colg] = yb;
            cs += yr; cq += yr * yr;
          }
        }
        atomicAdd(&s_sum[colg], cs);
        atomicAdd(&s_sq[colg], cq);
      }
    }
    __syncthreads();
    {
      float* slice = stats2 + (blockIdx.x & 7) * 256;
      if (tid < DD){
        atomicAdd(&slice[tid],      s_sum[tid]);
        atomicAdd(&slice[DD + tid], s_sq[tid]);
      }
    }
    gsync(bar, (++ep) * GRID);
    // ================= phase 3: BN2 (+ReLU) + residual, write h/hb =================
    if (tid < DD){
      float s = 0.f, q = 0.f;
      #pragma unroll
      for (int s8 = 0; s8 < 8; ++s8){
        s += stats2[s8 * 256 + tid];
        q += stats2[s8 * 256 + DD + tid];
      }
      float m   = s * (1.0f / NN);
      float var = q * (1.0f / NN) - m * m;
      float inv = rsqrtf(var + 1e-5f);
      float sc  = inv * g_out[l * DD + tid];
      s_scale[tid] = sc;
      s_shift[tid] = b_out[l * DD + tid] - m * sc;
    }
    if (blockIdx.x == 0){                         // zero stats1 for next layer
      #pragma unroll
      for (int j = 0; j < 8; ++j) stats1[j * 256 + tid] = 0.f;
    }
    __syncthreads();
    {
      int dorelu = (l < LL - 1);
      #pragma unroll
      for (int c0 = 0; c0 < 2; ++c0){
        int idx = tid + c0 * 256;
        int row = idx >> 4, co = (idx & 15) * 8;
        uint4 yv = *(const uint4*)(bufA + row * 136 + co);
        u32 yw[4] = {yv.x, yv.y, yv.z, yv.w};
        float4 scl0 = *(const float4*)(s_scale + co), scl1 = *(const float4*)(s_scale + co + 4);
        float4 shl0 = *(const float4*)(s_shift + co), shl1 = *(const float4*)(s_shift + co + 4);
        float scv[8] = {scl0.x, scl0.y, scl0.z, scl0.w, scl1.x, scl1.y, scl1.z, scl1.w};
        float shv[8] = {shl0.x, shl0.y, shl0.z, shl0.w, shl1.x, shl1.y, shl1.z, shl1.w};
        float v[8];
        #pragma unroll
        for (int j = 0; j < 4; ++j){
          v[2*j]     = bf2f(yw[j] & 0xFFFFu) * scv[2*j]     + shv[2*j];
          v[2*j + 1] = bf2f(yw[j] >> 16)     * scv[2*j + 1] + shv[2*j + 1];
        }
        if (dorelu){
          #pragma unroll
          for (int j = 0; j < 8; ++j) v[j] = fmaxf(v[j], 0.f);
        }
        float* hp = h + (row0 + row) * DD + co;
        float4 h0 = *(const float4*)hp;
        float4 h1 = *(const float4*)(hp + 4);
        h0.x += v[0]; h0.y += v[1]; h0.z += v[2]; h0.w += v[3];
        h1.x += v[4]; h1.y += v[5]; h1.z += v[6]; h1.w += v[7];
        *(float4*)hp = h0;
        *(float4*)(hp + 4) = h1;
        uint4 hpk;
        hpk.x = pack2(h0.x, h0.y); hpk.y = pack2(h0.z, h0.w);
        hpk.z = pack2(h1.x, h1.y); hpk.w = pack2(h1.z, h1.w);
        *(uint4*)(hb + (row0 + row) * 64 + (co >> 1)) = hpk;
      }
    }
    gsync(bar, (++ep) * GRID);
  }
}

extern "C" void kernel_launch(void* const* d_in, const int* in_sizes, int n_in,
                              void* d_out, int out_size, void* d_ws, size_t ws_size,
                              hipStream_t stream) {
  const int*   x_ids      = (const int*)d_in[0];
  const int*   edge_index = (const int*)d_in[1];
  const int*   edge_attr  = (const int*)d_in[2];
  const float* atom_emb   = (const float*)d_in[3];
  const float* bond_emb   = (const float*)d_in[4];
  const float* W1    = (const float*)d_in[5];
  const float* b1    = (const float*)d_in[6];
  const float* g1    = (const float*)d_in[7];
  const float* bt1   = (const float*)d_in[8];
  const float* W2    = (const float*)d_in[9];
  const float* b2    = (const float*)d_in[10];
  const float* eps   = (const float*)d_in[11];
  const float* g_out = (const float*)d_in[12];
  const float* b_out = (const float*)d_in[13];

  float* h     = (float*)d_out;               // NN*DD fp32 running node state
  u32*   store = (u32*)d_ws;                  // NB*CAP bin records
  u32*   hb    = store + NB * CAP;            // (NN+1)*64 bf16 mirror + sentinel
  u16*   wt    = (u16*)(hb + (NN + 1) * 64);  // 10*16384 bf16 transposed weights
  float* stats = (float*)(wt + 10 * 16384);   // 4096: stats1 | stats2
  int* rs      = (int*)(stats + 4096);        // NN+4
  int* rs2     = rs + NN + 4;                 // NN+4
  int* deg     = rs2 + NN + 4;                // NN
  int* col     = deg + NN;                    // EE + 3*NN
  int* bsum    = col + EE + 3 * NN;           // 64
  int* gcur    = bsum + 64;                   // 160
  int* bar     = gcur + 160;                  // 1

  k_pre   <<<5640, 256, 0, stream>>>(x_ids, atom_emb, h, hb, deg, W1, W2, wt, gcur);
  k_bin   <<<NB, 1024, 0, stream>>>(edge_index, edge_attr, deg, gcur, store);
  k_scan1 <<<40, 1024, 0, stream>>>(deg, rs, bsum);
  k_place2<<<NB, 1024, 0, stream>>>(store, gcur, rs, rs2, col, bsum, stats, bar);
  k_loop  <<<GRID, 256, 0, stream>>>(h, hb, rs2, col, bond_emb, eps, wt,
                                     b1, g1, bt1, b2, g_out, b_out, stats, bar);
}

// Round 13
// 439.039 us; speedup vs baseline: 5.8992x; 5.8992x over previous
//
#include <hip/hip_runtime.h>

#define NN 40000
#define EE 640000
#define DD 128
#define LL 5
#define NB 157          // buckets of 256 dst nodes
#define CAP 8192        // slots per bucket (mean ~4076, sigma ~64)

typedef unsigned short u16;
typedef unsigned int   u32;
typedef __attribute__((ext_vector_type(8))) short bf8;   // 8 bf16 = 4 VGPRs
typedef __attribute__((ext_vector_type(4))) float f4;

__device__ __forceinline__ float bf2f(u32 u){ union{u32 i; float f;} x; x.i = u << 16; return x.f; }
__device__ __forceinline__ u16 f2bf(float f){
  union{float f; u32 i;} x; x.f = f;
  u32 r = x.i + 0x7FFFu + ((x.i >> 16) & 1u);
  return (u16)(r >> 16);
}
__device__ __forceinline__ u32 pack2(float a, float b){ return (u32)f2bf(a) | ((u32)f2bf(b) << 16); }

// col packing: src[0:16] | attr<<17 | xid<<19   (sentinel: src=NN, xid=31)

// ---------------- prologue A: init h/deg/gcur + hb sentinel | wprep ----------------
// (main hb rows NOT initialized: layer-0 gather uses the LDS atom table; k_final l=0 writes hb)
__global__ void k_pre(const int* __restrict__ x_ids, const float* __restrict__ atom_emb,
                      float* __restrict__ h, u32* __restrict__ hb, int* __restrict__ deg,
                      const float* __restrict__ W1, const float* __restrict__ W2,
                      u16* __restrict__ wt, int* __restrict__ gcur){
  int bid = blockIdx.x, tid = threadIdx.x;
  if (bid < 5000){                                // init: NN*32 items (4 feats/thread)
    int idx = bid * 256 + tid;
    if (idx < NN) deg[idx] = 0;
    if (idx < 160) gcur[idx] = 0;
    if (idx < 32){ uint2 s; s.x = 0xFF80FF80u; s.y = 0xFF80FF80u;  // dummy node row: -inf
      ((uint2*)(hb + NN * 64))[idx] = s; }
    int n = idx >> 5, d4 = idx & 31;
    float4 v = ((const float4*)(atom_emb + x_ids[n] * DD))[d4];
    ((float4*)h)[idx] = v;
  } else {                                        // wprep: 10*16384 items
    int idx = (bid - 5000) * 256 + tid;
    int m = idx >> 14, nk = idx & 16383;
    int n = nk >> 7, k = nk & 127;
    const float* src = (m < LL) ? (W1 + m * 16384) : (W2 + (m - LL) * 16384);
    wt[idx] = f2bf(src[k * DD + n]);
  }
}

// ---------------- prologue B: count degrees + bucket edges ----------------
__global__ __launch_bounds__(1024) void k_bin(const int* __restrict__ ei, const int* __restrict__ ea,
                                              int* __restrict__ deg, int* __restrict__ gcur,
                                              u32* __restrict__ store){
  __shared__ int l_cnt[160];
  __shared__ int l_base[160];
  int tid = threadIdx.x;
  if (tid < 160) l_cnt[tid] = 0;
  __syncthreads();
  int e0 = blockIdx.x * 4096;                     // 157 x 4096 >= EE
  u32 rec[4]; int rb[4], rr[4];
  #pragma unroll
  for (int j = 0; j < 4; ++j){
    int e = e0 + j * 1024 + tid;
    rb[j] = -1;
    if (e < EE){
      int dst = ei[EE + e];
      atomicAdd(&deg[dst], 1);
      int b = dst >> 8;
      rb[j] = b;
      rr[j] = atomicAdd(&l_cnt[b], 1);
      rec[j] = (u32)ei[e] | ((u32)ea[e] << 16) | ((u32)(dst & 255) << 18);
    }
  }
  __syncthreads();
  if (tid < 160) l_base[tid] = atomicAdd(&gcur[tid], l_cnt[tid]);
  __syncthreads();
  #pragma unroll
  for (int j = 0; j < 4; ++j)
    if (rb[j] >= 0)
      store[rb[j] * CAP + l_base[rb[j]] + rr[j]] = rec[j];
}

// phase 1: per-block exclusive scan of degrees PADDED TO x8 + block totals (40 blocks x 1024)
__global__ void k_scan1(const int* __restrict__ deg, int* __restrict__ rs, int* __restrict__ bsum){
  __shared__ int buf[1024];
  int tid = threadIdx.x;
  int i = blockIdx.x * 1024 + tid;
  int dv = (i < NN) ? deg[i] : 0;
  int v = (dv + 7) & ~7;                         // pad each segment to x8 (16-wide gather groups)
  buf[tid] = v;
  __syncthreads();
  for (int off = 1; off < 1024; off <<= 1){
    int t = (tid >= off) ? buf[tid - off] : 0;
    __syncthreads();
    buf[tid] += t;
    __syncthreads();
  }
  int incl = buf[tid];
  if (i < NN) rs[i] = incl - v;                  // chunk-local exclusive
  if (tid == 1023) bsum[blockIdx.x] = incl;
}

// ---------------- place2: scan2-inline + scatter (with xid packing) + sentinel + stats1 zero ----------------
__global__ __launch_bounds__(1024) void k_place2(const u32* __restrict__ store, const int* __restrict__ gcur,
                                                 const int* __restrict__ rs, int* __restrict__ rs2,
                                                 int* __restrict__ col, const int* __restrict__ bsum,
                                                 float* __restrict__ stats1, const int* __restrict__ x_ids){
  __shared__ int l_cur[256];
  __shared__ int s_choff[41];
  int b = blockIdx.x, tid = threadIdx.x;
  if (b == 0){ stats1[tid] = 0.f; stats1[1024 + tid] = 0.f; }
  if (tid < 64){
    int v = (tid < 40) ? bsum[tid] : 0;
    #pragma unroll
    for (int off = 1; off < 64; off <<= 1){
      int t = __shfl_up(v, off, 64);
      if (tid >= off) v += t;
    }
    if (tid < 40){
      s_choff[tid] = v - bsum[tid];              // exclusive chunk offset
      if (tid == 39) s_choff[40] = v;            // padded total
    }
  }
  __syncthreads();
  int n0 = b << 8;
  if (tid < 256){
    int n = n0 + tid;
    if (n < NN){
      int g = rs[n] + s_choff[n >> 10];
      l_cur[tid] = g;
      rs2[n] = g;
    }
  }
  if (b == NB - 1 && tid == 0) rs2[NN] = s_choff[40];
  __syncthreads();
  int cnt = gcur[b];
  for (int r = tid; r < cnt; r += 1024){
    u32 rec = store[b * CAP + r];
    int dl = rec >> 18;
    int src = (int)(rec & 0xFFFFu);
    int attr = (int)((rec >> 16) & 3u);
    int xid = x_ids[src];                        // 0..27, L2-resident table
    int pos = atomicAdd(&l_cur[dl], 1);
    col[pos] = src | (attr << 17) | (xid << 19);
  }
  __syncthreads();
  if (tid < 256){                                 // pad gaps with sentinel (dummy node NN, xid 31)
    int n = n0 + tid;
    if (n < NN){
      int e = l_cur[tid];
      int end = (n + 1 < NN) ? (rs[n + 1] + s_choff[(n + 1) >> 10]) : s_choff[40];
      for (; e < end; ++e) col[e] = NN | (31 << 19);
    }
  }
}

// ---------------- FUSED gather + GEMM1 ----------------
// L0: gather sources come from the 32-row LDS atom table (rows 28..31 = -inf) instead of hb.
template<bool L0>
__global__ __launch_bounds__(256, 4) void k_gg(
    const float* __restrict__ h, const u32* __restrict__ hb,
    const int* __restrict__ row_start, const int* __restrict__ col,
    const float* __restrict__ bond_l, const float* __restrict__ eps_l,
    const u16* __restrict__ Wt, const float* __restrict__ bias,
    u16* __restrict__ out, float* __restrict__ osum, float* __restrict__ stats2,
    const float* __restrict__ atom_emb){
  __shared__ u16 sA[32 * 136];
  __shared__ float2 s_bond[4 * 64];
  __shared__ float s_eps;
  __shared__ float s_sum[DD], s_sq[DD];
  __shared__ u32 s_atom[L0 ? 32 * 64 : 64];       // L0 only: 32 rows x 128 bf16
  int tid = threadIdx.x;
  if (blockIdx.x == 0){                           // zero stats2 for this layer
    #pragma unroll
    for (int j = 0; j < 8; ++j) stats2[j * 256 + tid] = 0.f;
  }
  if (tid < 256) s_bond[tid] = ((const float2*)bond_l)[tid];
  if (tid == 0) s_eps = 1.0f + eps_l[0];
  if (tid < DD){ s_sum[tid] = 0.f; s_sq[tid] = 0.f; }
  if (L0){
    #pragma unroll
    for (int j = 0; j < 8; ++j){
      int idx = j * 256 + tid;                    // row = idx>>6, pair = idx&63
      int row = idx >> 6, pr = idx & 63;
      u32 v = 0xFF80FF80u;
      if (row < 28){
        float2 ae = ((const float2*)(atom_emb + row * DD))[pr];
        v = pack2(ae.x, ae.y);
      }
      s_atom[idx] = v;
    }
  }
  __syncthreads();
  int w = tid >> 6, lane = tid & 63;
  int vbase = blockIdx.x * 32 + w * 8;
  int sprev = __builtin_amdgcn_readfirstlane(row_start[vbase]);
  for (int j = 0; j < 8; ++j){
    int v = vbase + j;
    int send = __builtin_amdgcn_readfirstlane(row_start[v + 1]);  // multiple of 8
    int i = sprev; sprev = send;
    float accx[4] = {0.f, 0.f, 0.f, 0.f};
    float accy[4] = {0.f, 0.f, 0.f, 0.f};
    for (; i + 16 <= send; i += 16){              // 16 outstanding loads
      int4 c0 = *(const int4*)(col + i);
      int4 c1 = *(const int4*)(col + i + 4);
      int4 c2 = *(const int4*)(col + i + 8);
      int4 c3 = *(const int4*)(col + i + 12);
      int id[16] = {c0.x, c0.y, c0.z, c0.w, c1.x, c1.y, c1.z, c1.w,
                    c2.x, c2.y, c2.z, c2.w, c3.x, c3.y, c3.z, c3.w};
      u32 hx[16];
      #pragma unroll
      for (int q = 0; q < 16; ++q)
        hx[q] = L0 ? s_atom[((id[q] >> 19) & 31) * 64 + lane]
                   : hb[(id[q] & 0x1FFFF) * 64 + lane];
      #pragma unroll
      for (int q = 0; q < 16; ++q){
        float2 bb = s_bond[((id[q] >> 17) & 3) * 64 + lane];
        accx[q & 3] += fmaxf(bf2f(hx[q] & 0xFFFFu) + bb.x, 0.f);
        accy[q & 3] += fmaxf(bf2f(hx[q] >> 16)     + bb.y, 0.f);
      }
    }
    if (i < send){                                // exactly one 8-group remains
      int4 c0 = *(const int4*)(col + i);
      int4 c1 = *(const int4*)(col + i + 4);
      int id[8] = {c0.x, c0.y, c0.z, c0.w, c1.x, c1.y, c1.z, c1.w};
      u32 hx[8];
      #pragma unroll
      for (int q = 0; q < 8; ++q)
        hx[q] = L0 ? s_atom[((id[q] >> 19) & 31) * 64 + lane]
                   : hb[(id[q] & 0x1FFFF) * 64 + lane];
      #pragma unroll
      for (int q = 0; q < 8; ++q){
        float2 bb = s_bond[((id[q] >> 17) & 3) * 64 + lane];
        accx[q & 3] += fmaxf(bf2f(hx[q] & 0xFFFFu) + bb.x, 0.f);
        accy[q & 3] += fmaxf(bf2f(hx[q] >> 16)     + bb.y, 0.f);
      }
    }
    float2 hv = ((const float2*)h)[v * 64 + lane];
    u32 zp = pack2(s_eps * hv.x + (accx[0] + accx[1]) + (accx[2] + accx[3]),
                   s_eps * hv.y + (accy[0] + accy[1]) + (accy[2] + accy[3]));
    *(u32*)(sA + (w * 8 + j) * 136 + lane * 2) = zp;
  }
  int lr = lane & 15, lk = lane >> 4;
  bf8 bfr[2][4];
  #pragma unroll
  for (int nt = 0; nt < 2; ++nt){
    int n = w * 32 + nt * 16 + lr;
    #pragma unroll
    for (int kt = 0; kt < 4; ++kt)
      bfr[nt][kt] = *(const bf8*)(Wt + n * DD + kt * 32 + lk * 8);
  }
  __syncthreads();
  f4 acc[2][2];
  #pragma unroll
  for (int mt = 0; mt < 2; ++mt)
    #pragma unroll
    for (int nt = 0; nt < 2; ++nt) acc[mt][nt] = (f4){0.f, 0.f, 0.f, 0.f};
  #pragma unroll
  for (int kt = 0; kt < 4; ++kt){
    bf8 a0 = *(const bf8*)(sA + lr * 136        + kt * 32 + lk * 8);
    bf8 a1 = *(const bf8*)(sA + (16 + lr) * 136 + kt * 32 + lk * 8);
    acc[0][0] = __builtin_amdgcn_mfma_f32_16x16x32_bf16(a0, bfr[0][kt], acc[0][0], 0, 0, 0);
    acc[0][1] = __builtin_amdgcn_mfma_f32_16x16x32_bf16(a0, bfr[1][kt], acc[0][1], 0, 0, 0);
    acc[1][0] = __builtin_amdgcn_mfma_f32_16x16x32_bf16(a1, bfr[0][kt], acc[1][0], 0, 0, 0);
    acc[1][1] = __builtin_amdgcn_mfma_f32_16x16x32_bf16(a1, bfr[1][kt], acc[1][1], 0, 0, 0);
  }
  int row0 = blockIdx.x * 32;
  #pragma unroll
  for (int nt = 0; nt < 2; ++nt){
    int colg = w * 32 + nt * 16 + lr;
    float bv = bias[colg];
    float cs = 0.f, cq = 0.f;
    #pragma unroll
    for (int mt = 0; mt < 2; ++mt){
      #pragma unroll
      for (int r = 0; r < 4; ++r){
        u16 yb = f2bf(acc[mt][nt][r] + bv);
        float yr = bf2f(yb);
        out[(row0 + mt * 16 + lk * 4 + r) * DD + colg] = yb;
        cs += yr; cq += yr * yr;
      }
    }
    atomicAdd(&s_sum[colg], cs);
    atomicAdd(&s_sq[colg], cq);
  }
  __syncthreads();
  float* slice = osum + (blockIdx.x & 7) * 256;
  if (tid < DD){
    atomicAdd(&slice[tid],      s_sum[tid]);
    atomicAdd(&slice[DD + tid], s_sq[tid]);
  }
}

// ---------------- GEMM2: BN1+ReLU on input, MFMA @W2+b2, bf16 out + sliced stats2 ----------------
__global__ __launch_bounds__(256) void k_gemm2(const u16* __restrict__ Asrc,
    const u16* __restrict__ Wt, const float* __restrict__ bias,
    const float* __restrict__ stats_in,       // 8 slices x [sum128|sq128]
    const float* __restrict__ g, const float* __restrict__ bt,
    u16* __restrict__ out, float* __restrict__ osum){
  __shared__ u16 sA[32 * 136];
  __shared__ float s_scale[DD], s_shift[DD];
  __shared__ float s_sum[DD], s_sq[DD];
  int tid = threadIdx.x;
  int row0 = blockIdx.x * 32;
  if (tid < DD){
    s_sum[tid] = 0.f; s_sq[tid] = 0.f;
    float s = 0.f, q = 0.f;
    #pragma unroll
    for (int s8 = 0; s8 < 8; ++s8){
      s += stats_in[s8 * 256 + tid];
      q += stats_in[s8 * 256 + DD + tid];
    }
    float m   = s * (1.0f / NN);
    float var = q * (1.0f / NN) - m * m;
    float inv = rsqrtf(var + 1e-5f);
    float sc  = inv * g[tid];
    s_scale[tid] = sc;
    s_shift[tid] = bt[tid] - m * sc;
  }
  __syncthreads();
  #pragma unroll
  for (int c0 = 0; c0 < 2; ++c0){
    int c = tid + c0 * 256;
    int row = c >> 4, off = (c & 15) * 8;
    uint4 v = *(const uint4*)(Asrc + (row0 + row) * DD + off);
    u32 wv[4] = {v.x, v.y, v.z, v.w};
    union { u16 o[8]; uint4 v; } u;
    #pragma unroll
    for (int j = 0; j < 4; ++j){
      float y0 = bf2f(wv[j] & 0xFFFFu) * s_scale[off + 2*j]     + s_shift[off + 2*j];
      float y1 = bf2f(wv[j] >> 16)     * s_scale[off + 2*j + 1] + s_shift[off + 2*j + 1];
      u.o[2*j]     = f2bf(fmaxf(y0, 0.f));
      u.o[2*j + 1] = f2bf(fmaxf(y1, 0.f));
    }
    *(uint4*)(sA + row * 136 + off) = u.v;
  }
  int w = tid >> 6, lane = tid & 63, lr = lane & 15, lk = lane >> 4;
  bf8 bfr[2][4];
  #pragma unroll
  for (int nt = 0; nt < 2; ++nt){
    int n = w * 32 + nt * 16 + lr;
    #pragma unroll
    for (int kt = 0; kt < 4; ++kt)
      bfr[nt][kt] = *(const bf8*)(Wt + n * DD + kt * 32 + lk * 8);
  }
  __syncthreads();
  f4 acc[2][2];
  #pragma unroll
  for (int mt = 0; mt < 2; ++mt)
    #pragma unroll
    for (int nt = 0; nt < 2; ++nt) acc[mt][nt] = (f4){0.f, 0.f, 0.f, 0.f};
  #pragma unroll
  for (int kt = 0; kt < 4; ++kt){
    bf8 a0 = *(const bf8*)(sA + lr * 136        + kt * 32 + lk * 8);
    bf8 a1 = *(const bf8*)(sA + (16 + lr) * 136 + kt * 32 + lk * 8);
    acc[0][0] = __builtin_amdgcn_mfma_f32_16x16x32_bf16(a0, bfr[0][kt], acc[0][0], 0, 0, 0);
    acc[0][1] = __builtin_amdgcn_mfma_f32_16x16x32_bf16(a0, bfr[1][kt], acc[0][1], 0, 0, 0);
    acc[1][0] = __builtin_amdgcn_mfma_f32_16x16x32_bf16(a1, bfr[0][kt], acc[1][0], 0, 0, 0);
    acc[1][1] = __builtin_amdgcn_mfma_f32_16x16x32_bf16(a1, bfr[1][kt], acc[1][1], 0, 0, 0);
  }
  #pragma unroll
  for (int nt = 0; nt < 2; ++nt){
    int colg = w * 32 + nt * 16 + lr;
    float bv = bias[colg];
    float cs = 0.f, cq = 0.f;
    #pragma unroll
    for (int mt = 0; mt < 2; ++mt){
      #pragma unroll
      for (int r = 0; r < 4; ++r){
        u16 yb = f2bf(acc[mt][nt][r] + bv);
        float yr = bf2f(yb);
        out[(row0 + mt * 16 + lk * 4 + r) * DD + colg] = yb;
        cs += yr; cq += yr * yr;
      }
    }
    atomicAdd(&s_sum[colg], cs);
    atomicAdd(&s_sq[colg], cq);
  }
  __syncthreads();
  float* slice = osum + (blockIdx.x & 7) * 256;
  if (tid < DD){
    atomicAdd(&slice[tid],      s_sum[tid]);
    atomicAdd(&slice[DD + tid], s_sq[tid]);
  }
}

// ---------------- BN2 (+ReLU except last) + residual; 4 feats/thread; block 0 zeroes stats1 ----------------
__global__ void k_final(const u32* __restrict__ zf, const float* __restrict__ stats2,
                        const float* __restrict__ gl, const float* __restrict__ bl,
                        float* __restrict__ h, u32* __restrict__ hb, int do_relu,
                        float* __restrict__ stats1){
  __shared__ float s_scale[DD], s_shift[DD];
  int tid = threadIdx.x;
  if (blockIdx.x == 0){                           // zero stats1 for next layer's k_gg
    #pragma unroll
    for (int j = 0; j < 8; ++j) stats1[j * 256 + tid] = 0.f;
  }
  if (tid < DD){
    float s = 0.f, q = 0.f;
    #pragma unroll
    for (int s8 = 0; s8 < 8; ++s8){
      s += stats2[s8 * 256 + tid];
      q += stats2[s8 * 256 + DD + tid];
    }
    float m   = s * (1.0f / NN);
    float var = q * (1.0f / NN) - m * m;
    float inv = rsqrtf(var + 1e-5f);
    float sc  = inv * gl[tid];
    s_scale[tid] = sc;
    s_shift[tid] = bl[tid] - m * sc;
  }
  __syncthreads();
  int idx = blockIdx.x * 256 + tid;           // NN*32 items, 4 feats each
  int j0 = (idx & 31) * 4;
  uint2 zz = ((const uint2*)zf)[idx];
  float val0 = bf2f(zz.x & 0xFFFFu) * s_scale[j0]     + s_shift[j0];
  float val1 = bf2f(zz.x >> 16)     * s_scale[j0 + 1] + s_shift[j0 + 1];
  float val2 = bf2f(zz.y & 0xFFFFu) * s_scale[j0 + 2] + s_shift[j0 + 2];
  float val3 = bf2f(zz.y >> 16)     * s_scale[j0 + 3] + s_shift[j0 + 3];
  if (do_relu){
    val0 = fmaxf(val0, 0.f); val1 = fmaxf(val1, 0.f);
    val2 = fmaxf(val2, 0.f); val3 = fmaxf(val3, 0.f);
  }
  float4 hv = ((float4*)h)[idx];
  hv.x += val0; hv.y += val1; hv.z += val2; hv.w += val3;
  ((float4*)h)[idx] = hv;
  uint2 hp; hp.x = pack2(hv.x, hv.y); hp.y = pack2(hv.z, hv.w);
  ((uint2*)hb)[idx] = hp;
}

extern "C" void kernel_launch(void* const* d_in, const int* in_sizes, int n_in,
                              void* d_out, int out_size, void* d_ws, size_t ws_size,
                              hipStream_t stream) {
  const int*   x_ids      = (const int*)d_in[0];
  const int*   edge_index = (const int*)d_in[1];
  const int*   edge_attr  = (const int*)d_in[2];
  const float* atom_emb   = (const float*)d_in[3];
  const float* bond_emb   = (const float*)d_in[4];
  const float* W1    = (const float*)d_in[5];
  const float* b1    = (const float*)d_in[6];
  const float* g1    = (const float*)d_in[7];
  const float* bt1   = (const float*)d_in[8];
  const float* W2    = (const float*)d_in[9];
  const float* b2    = (const float*)d_in[10];
  const float* eps   = (const float*)d_in[11];
  const float* g_out = (const float*)d_in[12];
  const float* b_out = (const float*)d_in[13];

  float* h   = (float*)d_out;                 // NN*DD fp32 running node state
  u32*   zb  = (u32*)d_ws;                    // prologue: bin store; loop: unused
  u32*   z2b = zb  + NN * 64;                 // NN*64: bf16 gemm1 out
  u32*   zAb = z2b + NN * 64;                 // NN*64: bf16 gemm2 out
  u32*   hb  = zAb + NN * 64;                 // (NN+1)*64: bf16 mirror of h + sentinel row
  u16*   wt  = (u16*)(hb + (NN + 1) * 64);    // 10*16384 bf16 transposed weights
  float* stats = (float*)(wt + 10 * 16384);   // 4096: stats1[0..2047] | stats2[2048..4095]
  int* rs        = (int*)(stats + 4096);      // NN+4 (chunk-local scan)
  int* rs2       = rs + NN + 4;               // NN+4 (finalized row offsets)
  int* deg       = rs2 + NN + 4;
  int* col       = deg + NN;                  // EE + 7*NN (x8-padded)
  int* bsum      = col + EE + 7 * NN;         // 40
  int* gcur      = bsum + 64;                 // 160 bucket cursors

  u32* store = zb;                            // NB*CAP u32 records (5.1 MB; dead before loop)

  k_pre   <<<5640, 256, 0, stream>>>(x_ids, atom_emb, h, hb, deg, W1, W2, wt, gcur);
  k_bin   <<<NB, 1024, 0, stream>>>(edge_index, edge_attr, deg, gcur, store);
  k_scan1 <<<40, 1024, 0, stream>>>(deg, rs, bsum);
  k_place2<<<NB, 1024, 0, stream>>>(store, gcur, rs, rs2, col, bsum, stats, x_ids);

  for (int l = 0; l < LL; ++l){
    if (l == 0)
      k_gg<true> <<<NN / 32, 256, 0, stream>>>(h, hb, rs2, col,
                                               bond_emb + l * 4 * DD, eps + l,
                                               wt + l * 16384, b1 + l * DD,
                                               (u16*)z2b, stats, stats + 2048, atom_emb);
    else
      k_gg<false><<<NN / 32, 256, 0, stream>>>(h, hb, rs2, col,
                                               bond_emb + l * 4 * DD, eps + l,
                                               wt + l * 16384, b1 + l * DD,
                                               (u16*)z2b, stats, stats + 2048, atom_emb);
    k_gemm2<<<NN / 32, 256, 0, stream>>>((const u16*)z2b, wt + (LL + l) * 16384, b2 + l * DD,
                                         stats, g1 + l * DD, bt1 + l * DD,
                                         (u16*)zAb, stats + 2048);
    k_final<<<NN * 32 / 256, 256, 0, stream>>>(zAb, stats + 2048,
                                               g_out + l * DD, b_out + l * DD,
                                               h, hb, (l < LL - 1) ? 1 : 0, stats);
  }
}